// Round 4
// baseline (768.602 us; speedup 1.0000x reference)
//
#include <hip/hip_runtime.h>

// ---------------------------------------------------------------------------
// QuantMLP r8: (1) gemm1 LDS-read phase REBALANCE. r5/r6/r7 all pinned at
// MfmaUtil 37-41%: per-tile time == MFMA(2484cyc) + LDS reads(2304cyc) run
// SERIALLY because reads were distributed 4/8/0/12 per phase (p3's 12 forced
// after the vmcnt since tile-t+1 was only confirmed there) -- max-phase LDS
// 1152cyc vs 620cyc matrix-phase, barrier-locked. Fix: vmcnt(4) moved to
// BARRIER1 (A/B(t+1) in flight >=1.25 tiles, wait is free) so t+1 fragment
// reads start at p2 -> distribution 8/4/4/8 (max 768cyc). Math order per acc
// element unchanged -> bitwise identical (absmax 0.06640625).
// (2) gemm2 ported to the same 256x256 pipelined structure (BK=128 i8 ->
// byte-identical LDS layout/swizzle/staging to gemm1). Grid = 256 blocks =
// exactly 1/CU. int32 accumulation is associative -> bitwise-safe.
// Shapes: T=8192 tokens, H=2048, I=5632.
// ---------------------------------------------------------------------------

#define DEVI __device__ __forceinline__

typedef _Float16 half8 __attribute__((ext_vector_type(8)));
typedef _Float16 half4v __attribute__((ext_vector_type(4)));
typedef float floatx4 __attribute__((ext_vector_type(4)));
typedef int int4v __attribute__((ext_vector_type(4)));
typedef signed char char8v __attribute__((ext_vector_type(8)));

static constexpr int T_TOK = 8192;   // B*S
static constexpr int H_DIM = 2048;
static constexpr int I_DIM = 5632;
static constexpr int N1 = 2 * I_DIM; // 11264: interleaved [16 gate | 16 up]*

DEVI void load16_lds(const void* g, void* l) {
    __builtin_amdgcn_global_load_lds(
        (const __attribute__((address_space(1))) unsigned int*)g,
        (__attribute__((address_space(3))) unsigned int*)l,
        16 /*bytes*/, 0 /*offset*/, 0 /*aux*/);
}

DEVI float block_amax_256(float v, float* sbuf) {
    #pragma unroll
    for (int off = 32; off; off >>= 1)
        v = fmaxf(v, __shfl_xor(v, off, 64));
    if ((threadIdx.x & 63) == 0) sbuf[threadIdx.x >> 6] = v;
    __syncthreads();
    return fmaxf(fmaxf(sbuf[0], sbuf[1]), fmaxf(sbuf[2], sbuf[3]));
}

// ------------------------- init per-token amax ------------------------------
__global__ __launch_bounds__(256) void init_amax_kernel(int* __restrict__ a) {
    a[blockIdx.x * 256 + threadIdx.x] = 0;  // float 0.0 bit pattern
}

// ------------------ Wg/Wu 4-bit fake-quant, interleaved out -----------------
// source row i -> dest row (i>>4)*32 + HALF*16 + (i&15)  (HALF: 0=gate,1=up)
template <int HALF>
__global__ __launch_bounds__(256) void quant_ug_kernel(
    const float* __restrict__ in, _Float16* __restrict__ out) {
    __shared__ float sbuf[4];
    const int i = blockIdx.x;
    const int orow = ((i >> 4) * 32) + HALF * 16 + (i & 15);
    const float* r = in + (size_t)i * H_DIM;
    _Float16* o = out + (size_t)orow * H_DIM;
    float v[8];
    float amax = 0.f;
    #pragma unroll
    for (int j = 0; j < 8; ++j) {
        v[j] = r[threadIdx.x + j * 256];
        amax = fmaxf(amax, fabsf(v[j]));
    }
    amax = block_amax_256(amax, sbuf);
    const float scale = fmaxf(amax / 7.f, 1e-8f);
    #pragma unroll
    for (int j = 0; j < 8; ++j) {
        float q = rintf(v[j] / scale);
        q = fminf(fmaxf(q, -7.f), 7.f);
        o[threadIdx.x + j * 256] = (_Float16)(q * scale);
    }
}

// ------------------ Wd 4-bit quant -> int8 codes + scale --------------------
__global__ __launch_bounds__(256) void quant_wd_i8_kernel(
    const float* __restrict__ in, signed char* __restrict__ qw,
    float* __restrict__ sw) {
    __shared__ float sbuf[4];
    const size_t row = blockIdx.x;
    const float* r = in + row * (size_t)I_DIM;
    signed char* o = qw + row * (size_t)I_DIM;
    float v[22];
    float amax = 0.f;
    #pragma unroll
    for (int j = 0; j < 22; ++j) {
        v[j] = r[threadIdx.x + j * 256];
        amax = fmaxf(amax, fabsf(v[j]));
    }
    amax = block_amax_256(amax, sbuf);
    const float scale = fmaxf(amax / 7.f, 1e-8f);
    if (threadIdx.x == 0) sw[row] = scale;
    #pragma unroll
    for (int j = 0; j < 22; ++j) {
        float q = rintf(v[j] / scale);
        q = fminf(fmaxf(q, -7.f), 7.f);
        o[threadIdx.x + j * 256] = (signed char)q;
    }
}

// --------------------------- x cast fp32 -> fp16 ----------------------------
__global__ __launch_bounds__(256) void cast_x_kernel(
    const float* __restrict__ in, _Float16* __restrict__ out) {
    const size_t i = ((size_t)blockIdx.x * 256 + threadIdx.x) * 4;
    floatx4 f = *(const floatx4*)(in + i);
    half4v h;
    h.x = (_Float16)f.x; h.y = (_Float16)f.y;
    h.z = (_Float16)f.z; h.w = (_Float16)f.w;
    *(half4v*)(out + i) = h;
}

// ---------------- GEMM1: 256x256 tile, BK=64, 8 waves, balanced reads -------
// LDS 160 KiB: A [3 buf][2 half][128][64] f16 (96 KiB, buf = t%3),
//              B [2 buf][2 half][128][64] f16 (64 KiB, buf = t&1).
// Per tile t (reads >=1 phase ahead of their MFMA, 8/4/4/8 per phase):
//   p0: read bf1(t)[4]+af1(t)[mi0,1][4]; STAGE A(t+2,h0) | M00 = af0*bf0
//   p1: read af1(t)[mi2,3][4];           STAGE A(t+2,h1) | M01 = af0*bf1
//       vmcnt(4) [A(t+1),B(t+1) confirmed; A(t+2) in flight]; BARRIER1
//   p2: read af0(t+1)[mi0,1][4];         STAGE B(t+2,h0+h1) | M10 = af1*bf0
//   p3: read af0(t+1)[mi2,3][4]+bf0(t+1)[4]               | M11 = af1*bf1
//       BARRIER2
// BARRIER1: staged-data visibility for p2/p3 next-tile reads; also all
// waves' bf1(t) reads done (M01 lgkm) before p2 overwrites B-buf bufb.
// BARRIER2: all waves' buf-ra reads done (M00..M11 lgkm waits) before
// p0(t+1) stages A(t+3) into (t+3)%3 == ra.
__global__ __launch_bounds__(512, 2) void gemm1_fused_kernel(
    const _Float16* __restrict__ A,   // xh [8192][2048]
    const _Float16* __restrict__ B,   // Wq_ug interleaved [11264][2048]
    _Float16* __restrict__ mulh,      // [8192][5632]
    int* __restrict__ amax_bits) {    // [8192], pre-zeroed
    __shared__ __align__(16) _Float16 As[3 * 2 * 128 * 64];  // 96 KiB
    __shared__ __align__(16) _Float16 Bs[2 * 2 * 128 * 64];  // 64 KiB

    constexpr int NT = H_DIM / 64;            // 32 K-tiles
    constexpr int NXB = N1 / 256;             // 44
    constexpr int NWG = (T_TOK / 256) * NXB;  // 1408 (divisible by 8)

    const int tid = threadIdx.x;
    const int lane = tid & 63;
    const int w = tid >> 6;        // 0..7
    const int wm = w >> 2;         // 0..1 (M half)
    const int wn = w & 3;          // 0..3 (N quarter)
    const int fr = lane & 15;
    const int q = lane >> 4;

    // XCD-aware swizzle (bijective: NWG % 8 == 0)
    int wg = blockIdx.x;
    wg = (wg & 7) * (NWG / 8) + (wg >> 3);
    const int by = wg / NXB;
    const int bx = wg - by * NXB;
    const int row0 = by * 256;
    const int col0 = bx * 256;

    // ---- staging addressing: linear LDS dest, inverse-swizzled global src --
    const int sr = tid >> 3;                         // 0..63
    const int sc = ((tid & 7) ^ (sr & 7)) << 3;      // swizzled col (f16)
    const _Float16* gA = A + (size_t)(row0 + sr) * H_DIM + sc;
    const _Float16* gB = B + (size_t)(col0 + sr) * H_DIM + sc;
    _Float16* lA = As + tid * 8;
    _Float16* lB = Bs + tid * 8;

    #define STAGE_A(t, h, buf) do {                                          \
        const _Float16* s_ = gA + (size_t)((h) * 128) * H_DIM + (t) * 64;    \
        _Float16* d_ = lA + ((buf) * 2 + (h)) * 8192;                        \
        load16_lds(s_, d_);                                                  \
        load16_lds(s_ + (size_t)64 * H_DIM, d_ + 4096);                      \
    } while (0)
    #define STAGE_B(t, h, buf) do {                                          \
        const _Float16* s_ = gB + (size_t)((h) * 128) * H_DIM + (t) * 64;    \
        _Float16* d_ = lB + ((buf) * 2 + (h)) * 8192;                        \
        load16_lds(s_, d_);                                                  \
        load16_lds(s_ + (size_t)64 * H_DIM, d_ + 4096);                      \
    } while (0)

    // ---- ds_read addressing (swizzled): elem = row*64 + (slot^(row&7))*8 --
    int coff[2];
    coff[0] = ((0 + q) ^ (fr & 7)) * 8;   // kk=0 slots 0..3
    coff[1] = ((4 + q) ^ (fr & 7)) * 8;   // kk=1 slots 4..7
    const int aro = wm * 8192 + fr * 64;                        // A half = wm
    const int bro = (wn >> 1) * 8192 + ((wn & 1) * 64 + fr) * 64;

    floatx4 acc[8][4] = {};
    half8 af0[4][2], af1[4][2], bf0[2][2], bf1[2][2];

    // ------------------------------- prologue -------------------------------
    // issue order: A(0) B(0) A(1) B(1) -> vmcnt(8) waits A(0),B(0)
    STAGE_A(0, 0, 0); STAGE_A(0, 1, 0);
    STAGE_B(0, 0, 0); STAGE_B(0, 1, 0);
    STAGE_A(1, 0, 1); STAGE_A(1, 1, 1);
    STAGE_B(1, 0, 1); STAGE_B(1, 1, 1);
    asm volatile("s_waitcnt vmcnt(8)" ::: "memory");  // A(0),B(0) resident
    __builtin_amdgcn_s_barrier();
    __builtin_amdgcn_sched_barrier(0);
    // pre-read tile-0 af0/bf0 (bufs 0)
    #pragma unroll
    for (int mi = 0; mi < 4; ++mi)
        #pragma unroll
        for (int kk = 0; kk < 2; ++kk)
            af0[mi][kk] = *(const half8*)(As + aro + mi * 1024 + coff[kk]);
    #pragma unroll
    for (int ni = 0; ni < 2; ++ni)
        #pragma unroll
        for (int kk = 0; kk < 2; ++kk)
            bf0[ni][kk] = *(const half8*)(Bs + bro + ni * 1024 + coff[kk]);

    int ra = 0;  // A read buf = t%3
    for (int t = 0; t < NT; ++t) {
        const int bufb = t & 1;
        const int na = (ra == 2) ? 0 : ra + 1;   // (t+1)%3
        const int wa = (na == 2) ? 0 : na + 1;   // (t+2)%3
        const int ab = ra * 16384 + aro;
        const int bb = bufb * 16384 + bro;
        const int nab = na * 16384 + aro;
        const int nbb = (bufb ^ 1) * 16384 + bro;

        // ---- p0: read bf1(t) + af1(t)[mi0,1]; STAGE A(t+2,h0); M00 --------
        #pragma unroll
        for (int ni = 0; ni < 2; ++ni)
            #pragma unroll
            for (int kk = 0; kk < 2; ++kk)
                bf1[ni][kk] =
                    *(const half8*)(Bs + bb + (2 + ni) * 1024 + coff[kk]);
        #pragma unroll
        for (int mi = 0; mi < 2; ++mi)
            #pragma unroll
            for (int kk = 0; kk < 2; ++kk)
                af1[mi][kk] =
                    *(const half8*)(As + ab + (4 + mi) * 1024 + coff[kk]);
        if (t + 2 < NT) STAGE_A(t + 2, 0, wa);
        __builtin_amdgcn_s_setprio(1);
        #pragma unroll
        for (int mi = 0; mi < 4; ++mi)
            #pragma unroll
            for (int ni = 0; ni < 2; ++ni)
                #pragma unroll
                for (int kk = 0; kk < 2; ++kk)
                    acc[mi][ni] = __builtin_amdgcn_mfma_f32_16x16x32_f16(
                        af0[mi][kk], bf0[ni][kk], acc[mi][ni], 0, 0, 0);
        __builtin_amdgcn_s_setprio(0);

        // ---- p1: read af1(t)[mi2,3]; STAGE A(t+2,h1); M01; vmcnt; BARRIER1
        #pragma unroll
        for (int mi = 2; mi < 4; ++mi)
            #pragma unroll
            for (int kk = 0; kk < 2; ++kk)
                af1[mi][kk] =
                    *(const half8*)(As + ab + (4 + mi) * 1024 + coff[kk]);
        if (t + 2 < NT) STAGE_A(t + 2, 1, wa);
        __builtin_amdgcn_s_setprio(1);
        #pragma unroll
        for (int mi = 0; mi < 4; ++mi)
            #pragma unroll
            for (int ni = 0; ni < 2; ++ni)
                #pragma unroll
                for (int kk = 0; kk < 2; ++kk)
                    acc[mi][2 + ni] = __builtin_amdgcn_mfma_f32_16x16x32_f16(
                        af0[mi][kk], bf1[ni][kk], acc[mi][2 + ni], 0, 0, 0);
        __builtin_amdgcn_s_setprio(0);
        if (t + 2 < NT)
            asm volatile("s_waitcnt vmcnt(4)" ::: "memory");  // t+1 resident
        else
            asm volatile("s_waitcnt vmcnt(0)" ::: "memory");  // tail drain
        __builtin_amdgcn_s_barrier();          // BARRIER1
        __builtin_amdgcn_sched_barrier(0);

        // ---- p2: read af0(t+1)[mi0,1]; STAGE B(t+2,h0+h1); M10 ------------
        if (t + 1 < NT) {
            #pragma unroll
            for (int mi = 0; mi < 2; ++mi)
                #pragma unroll
                for (int kk = 0; kk < 2; ++kk)
                    af0[mi][kk] =
                        *(const half8*)(As + nab + mi * 1024 + coff[kk]);
        }
        if (t + 2 < NT) { STAGE_B(t + 2, 0, bufb); STAGE_B(t + 2, 1, bufb); }
        __builtin_amdgcn_s_setprio(1);
        #pragma unroll
        for (int mi = 0; mi < 4; ++mi)
            #pragma unroll
            for (int ni = 0; ni < 2; ++ni)
                #pragma unroll
                for (int kk = 0; kk < 2; ++kk)
                    acc[4 + mi][ni] = __builtin_amdgcn_mfma_f32_16x16x32_f16(
                        af1[mi][kk], bf0[ni][kk], acc[4 + mi][ni], 0, 0, 0);
        __builtin_amdgcn_s_setprio(0);

        // ---- p3: read af0(t+1)[mi2,3] + bf0(t+1); M11; BARRIER2 -----------
        if (t + 1 < NT) {
            #pragma unroll
            for (int mi = 2; mi < 4; ++mi)
                #pragma unroll
                for (int kk = 0; kk < 2; ++kk)
                    af0[mi][kk] =
                        *(const half8*)(As + nab + mi * 1024 + coff[kk]);
            #pragma unroll
            for (int ni = 0; ni < 2; ++ni)
                #pragma unroll
                for (int kk = 0; kk < 2; ++kk)
                    bf0[ni][kk] =
                        *(const half8*)(Bs + nbb + ni * 1024 + coff[kk]);
        }
        __builtin_amdgcn_s_setprio(1);
        #pragma unroll
        for (int mi = 0; mi < 4; ++mi)
            #pragma unroll
            for (int ni = 0; ni < 2; ++ni)
                #pragma unroll
                for (int kk = 0; kk < 2; ++kk)
                    acc[4 + mi][2 + ni] =
                        __builtin_amdgcn_mfma_f32_16x16x32_f16(
                            af1[mi][kk], bf1[ni][kk], acc[4 + mi][2 + ni],
                            0, 0, 0);
        __builtin_amdgcn_s_setprio(0);
        __builtin_amdgcn_s_barrier();          // BARRIER2
        __builtin_amdgcn_sched_barrier(0);
        ra = na;
    }
    #undef STAGE_A
    #undef STAGE_B

    // ---- fused epilogue: silu(gate)*up in-register + per-token amax --------
    const int q4 = q * 4;
    const int lc = fr;
    _Float16* mbase = mulh + bx * 128 + wn * 32 + lc;
    #pragma unroll
    for (int mi = 0; mi < 8; ++mi) {
        #pragma unroll
        for (int i = 0; i < 4; ++i) {
            const int r = row0 + wm * 128 + mi * 16 + q4 + i;
            float rmax = 0.f;
            _Float16* mrow = mbase + (size_t)r * I_DIM;
            #pragma unroll
            for (int p = 0; p < 2; ++p) {
                const float g = acc[mi][2 * p][i];
                const float u = acc[mi][2 * p + 1][i];
                const float m = g / (1.f + expf(-g)) * u;  // silu(g)*u
                mrow[p * 16] = (_Float16)m;
                rmax = fmaxf(rmax, fabsf(m));
            }
            #pragma unroll
            for (int off = 1; off < 16; off <<= 1)
                rmax = fmaxf(rmax, __shfl_xor(rmax, off, 64));
            if (lc == 0)
                atomicMax(&amax_bits[r], __float_as_int(rmax));
        }
    }
}

// ---------------- per-token 8-bit quant: fp16 mul -> int8 codes -------------
__global__ __launch_bounds__(256) void act_quant_kernel(
    const _Float16* __restrict__ mulh, const int* __restrict__ amax_bits,
    signed char* __restrict__ qa, float* __restrict__ sa) {
    const size_t t = blockIdx.x;
    const float amax = __int_as_float(amax_bits[t]);
    const float s = fmaxf(amax / 127.f, 1e-8f);
    if (threadIdx.x == 0) sa[t] = s;
    const float rs = 1.f / s;
    const _Float16* mrow = mulh + t * I_DIM;
    signed char* qrow = qa + t * I_DIM;
    for (int c = threadIdx.x; c < I_DIM / 8; c += 256) {
        half8 v = *(const half8*)(mrow + c * 8);
        char8v q;
        #pragma unroll
        for (int j = 0; j < 8; ++j) {
            float f = rintf((float)v[j] * rs);
            f = fminf(fmaxf(f, -127.f), 127.f);
            q[j] = (signed char)f;
        }
        *(char8v*)(qrow + c * 8) = q;
    }
}

// ------------- GEMM2: int8 down-proj, 256x256 pipelined (exact) -------------
// Same structure/schedule as gemm1 (BK=128 i8 -> byte-identical LDS layout:
// [128 rows][128B] halves, same swizzle/staging/fragment geometry).
// NT=44 K-tiles; grid = 256 blocks = exactly 1/CU. int32 accum = associative
// -> bitwise identical results to any schedule.
__global__ __launch_bounds__(512, 2) void gemm2_i8_kernel(
    const signed char* __restrict__ A,  // qa [8192][5632]
    const signed char* __restrict__ B,  // Qw_d [2048][5632]
    const float* __restrict__ sa, const float* __restrict__ sw,
    float* __restrict__ C) {            // [8192][2048]
    __shared__ __align__(16) signed char As[3 * 2 * 128 * 128];  // 96 KiB
    __shared__ __align__(16) signed char Bs[2 * 2 * 128 * 128];  // 64 KiB

    constexpr int NT = I_DIM / 128;           // 44 K-tiles
    constexpr int NXB = H_DIM / 256;          // 8
    constexpr int NWG = (T_TOK / 256) * NXB;  // 256 (exactly 1/CU)

    const int tid = threadIdx.x;
    const int lane = tid & 63;
    const int w = tid >> 6;
    const int wm = w >> 2;         // 0..1
    const int wn = w & 3;          // 0..3
    const int fr = lane & 15;
    const int q = lane >> 4;

    int wg = blockIdx.x;
    wg = (wg & 7) * (NWG / 8) + (wg >> 3);   // XCD swizzle, bijective
    const int by = wg / NXB;
    const int bx = wg - by * NXB;
    const int row0 = by * 256;
    const int col0 = bx * 256;

    // staging: linear LDS dest, inverse-swizzled global src (16B units)
    const int sr = tid >> 3;                          // 0..63
    const int scb = ((tid & 7) ^ (sr & 7)) << 4;      // swizzled byte col
    const signed char* gA = A + (size_t)(row0 + sr) * I_DIM + scb;
    const signed char* gB = B + (size_t)(col0 + sr) * I_DIM + scb;
    signed char* lA = As + tid * 16;
    signed char* lB = Bs + tid * 16;

    #define STAGE_A2(t, h, buf) do {                                         \
        const signed char* s_ = gA + (size_t)((h) * 128) * I_DIM + (t) * 128;\
        signed char* d_ = lA + ((buf) * 2 + (h)) * 16384;                    \
        load16_lds(s_, d_);                                                  \
        load16_lds(s_ + (size_t)64 * I_DIM, d_ + 8192);                      \
    } while (0)
    #define STAGE_B2(t, h, buf) do {                                         \
        const signed char* s_ = gB + (size_t)((h) * 128) * I_DIM + (t) * 128;\
        signed char* d_ = lB + ((buf) * 2 + (h)) * 16384;                    \
        load16_lds(s_, d_);                                                  \
        load16_lds(s_ + (size_t)64 * I_DIM, d_ + 8192);                      \
    } while (0)

    // ds_read (swizzled): byte = row*128 + ((kk*4+q)^(row&7))*16
    int coff[2];
    coff[0] = ((0 + q) ^ (fr & 7)) * 16;
    coff[1] = ((4 + q) ^ (fr & 7)) * 16;
    const int aro = wm * 16384 + fr * 128;
    const int bro = (wn >> 1) * 16384 + ((wn & 1) * 64 + fr) * 128;

    int4v acc[8][4] = {};
    int4v af0[4][2], af1[4][2], bf0[2][2], bf1[2][2];

    // prologue
    STAGE_A2(0, 0, 0); STAGE_A2(0, 1, 0);
    STAGE_B2(0, 0, 0); STAGE_B2(0, 1, 0);
    STAGE_A2(1, 0, 1); STAGE_A2(1, 1, 1);
    STAGE_B2(1, 0, 1); STAGE_B2(1, 1, 1);
    asm volatile("s_waitcnt vmcnt(8)" ::: "memory");
    __builtin_amdgcn_s_barrier();
    __builtin_amdgcn_sched_barrier(0);
    #pragma unroll
    for (int mi = 0; mi < 4; ++mi)
        #pragma unroll
        for (int kk = 0; kk < 2; ++kk)
            af0[mi][kk] = *(const int4v*)(As + aro + mi * 2048 + coff[kk]);
    #pragma unroll
    for (int ni = 0; ni < 2; ++ni)
        #pragma unroll
        for (int kk = 0; kk < 2; ++kk)
            bf0[ni][kk] = *(const int4v*)(Bs + bro + ni * 2048 + coff[kk]);

    int ra = 0;
    for (int t = 0; t < NT; ++t) {
        const int bufb = t & 1;
        const int na = (ra == 2) ? 0 : ra + 1;
        const int wa = (na == 2) ? 0 : na + 1;
        const int ab = ra * 32768 + aro;
        const int bb = bufb * 32768 + bro;
        const int nab = na * 32768 + aro;
        const int nbb = (bufb ^ 1) * 32768 + bro;

        // p0
        #pragma unroll
        for (int ni = 0; ni < 2; ++ni)
            #pragma unroll
            for (int kk = 0; kk < 2; ++kk)
                bf1[ni][kk] =
                    *(const int4v*)(Bs + bb + (2 + ni) * 2048 + coff[kk]);
        #pragma unroll
        for (int mi = 0; mi < 2; ++mi)
            #pragma unroll
            for (int kk = 0; kk < 2; ++kk)
                af1[mi][kk] =
                    *(const int4v*)(As + ab + (4 + mi) * 2048 + coff[kk]);
        if (t + 2 < NT) STAGE_A2(t + 2, 0, wa);
        __builtin_amdgcn_s_setprio(1);
        #pragma unroll
        for (int mi = 0; mi < 4; ++mi)
            #pragma unroll
            for (int ni = 0; ni < 2; ++ni)
                #pragma unroll
                for (int kk = 0; kk < 2; ++kk)
                    acc[mi][ni] = __builtin_amdgcn_mfma_i32_16x16x64_i8(
                        af0[mi][kk], bf0[ni][kk], acc[mi][ni], 0, 0, 0);
        __builtin_amdgcn_s_setprio(0);

        // p1
        #pragma unroll
        for (int mi = 2; mi < 4; ++mi)
            #pragma unroll
            for (int kk = 0; kk < 2; ++kk)
                af1[mi][kk] =
                    *(const int4v*)(As + ab + (4 + mi) * 2048 + coff[kk]);
        if (t + 2 < NT) STAGE_A2(t + 2, 1, wa);
        __builtin_amdgcn_s_setprio(1);
        #pragma unroll
        for (int mi = 0; mi < 4; ++mi)
            #pragma unroll
            for (int ni = 0; ni < 2; ++ni)
                #pragma unroll
                for (int kk = 0; kk < 2; ++kk)
                    acc[mi][2 + ni] = __builtin_amdgcn_mfma_i32_16x16x64_i8(
                        af0[mi][kk], bf1[ni][kk], acc[mi][2 + ni], 0, 0, 0);
        __builtin_amdgcn_s_setprio(0);
        if (t + 2 < NT)
            asm volatile("s_waitcnt vmcnt(4)" ::: "memory");
        else
            asm volatile("s_waitcnt vmcnt(0)" ::: "memory");
        __builtin_amdgcn_s_barrier();          // BARRIER1
        __builtin_amdgcn_sched_barrier(0);

        // p2
        if (t + 1 < NT) {
            #pragma unroll
            for (int mi = 0; mi < 2; ++mi)
                #pragma unroll
                for (int kk = 0; kk < 2; ++kk)
                    af0[mi][kk] =
                        *(const int4v*)(As + nab + mi * 2048 + coff[kk]);
        }
        if (t + 2 < NT) { STAGE_B2(t + 2, 0, bufb); STAGE_B2(t + 2, 1, bufb); }
        __builtin_amdgcn_s_setprio(1);
        #pragma unroll
        for (int mi = 0; mi < 4; ++mi)
            #pragma unroll
            for (int ni = 0; ni < 2; ++ni)
                #pragma unroll
                for (int kk = 0; kk < 2; ++kk)
                    acc[4 + mi][ni] = __builtin_amdgcn_mfma_i32_16x16x64_i8(
                        af1[mi][kk], bf0[ni][kk], acc[4 + mi][ni], 0, 0, 0);
        __builtin_amdgcn_s_setprio(0);

        // p3
        if (t + 1 < NT) {
            #pragma unroll
            for (int mi = 2; mi < 4; ++mi)
                #pragma unroll
                for (int kk = 0; kk < 2; ++kk)
                    af0[mi][kk] =
                        *(const int4v*)(As + nab + mi * 2048 + coff[kk]);
            #pragma unroll
            for (int ni = 0; ni < 2; ++ni)
                #pragma unroll
                for (int kk = 0; kk < 2; ++kk)
                    bf0[ni][kk] =
                        *(const int4v*)(Bs + nbb + ni * 2048 + coff[kk]);
        }
        __builtin_amdgcn_s_setprio(1);
        #pragma unroll
        for (int mi = 0; mi < 4; ++mi)
            #pragma unroll
            for (int ni = 0; ni < 2; ++ni)
                #pragma unroll
                for (int kk = 0; kk < 2; ++kk)
                    acc[4 + mi][2 + ni] =
                        __builtin_amdgcn_mfma_i32_16x16x64_i8(
                            af1[mi][kk], bf1[ni][kk], acc[4 + mi][2 + ni],
                            0, 0, 0);
        __builtin_amdgcn_s_setprio(0);
        __builtin_amdgcn_s_barrier();          // BARRIER2
        __builtin_amdgcn_sched_barrier(0);
        ra = na;
    }
    #undef STAGE_A2
    #undef STAGE_B2

    // epilogue: scale and store
    const int q4 = q * 4;
    float sw4[4];
    #pragma unroll
    for (int ni = 0; ni < 4; ++ni)
        sw4[ni] = sw[col0 + wn * 64 + ni * 16 + fr];
    #pragma unroll
    for (int mi = 0; mi < 8; ++mi) {
        #pragma unroll
        for (int i = 0; i < 4; ++i) {
            const int r = row0 + wm * 128 + mi * 16 + q4 + i;
            const float s_r = sa[r];
            float* crow = C + (size_t)r * H_DIM + col0 + wn * 64 + fr;
            #pragma unroll
            for (int ni = 0; ni < 4; ++ni)
                crow[ni * 16] = (float)acc[mi][ni][i] * s_r * sw4[ni];
        }
    }
}

// ---------------------------------------------------------------------------
extern "C" void kernel_launch(void* const* d_in, const int* in_sizes, int n_in,
                              void* d_out, int out_size, void* d_ws, size_t ws_size,
                              hipStream_t stream) {
    const float* x  = (const float*)d_in[0];   // [8192, 2048]
    const float* Wg = (const float*)d_in[1];   // [5632, 2048]
    const float* Wu = (const float*)d_in[2];   // [5632, 2048]
    const float* Wd = (const float*)d_in[3];   // [2048, 5632]
    float* out = (float*)d_out;                // [8192, 2048] = 64 MiB

    char* ws = (char*)d_ws;
    const size_t SZ_WUG  = (size_t)N1 * H_DIM * 2;     // 46,137,344
    const size_t SZ_MULH = (size_t)T_TOK * I_DIM * 2;  // 92,274,688
    const size_t SZ_QA   = (size_t)T_TOK * I_DIM;      // 46,137,344
    const size_t SZ_QWD  = (size_t)H_DIM * I_DIM;      // 11,534,336
    _Float16*    Wq_ug = (_Float16*)ws;
    _Float16*    mulh  = (_Float16*)(ws + SZ_WUG);
    signed char* qa    = (signed char*)(ws + SZ_WUG + SZ_MULH);
    signed char* Qw_d  = (signed char*)(ws + SZ_WUG + SZ_MULH + SZ_QA);
    char* tail = ws + SZ_WUG + SZ_MULH + SZ_QA + SZ_QWD;
    float* sw        = (float*)tail;                    // [2048]
    float* sa        = (float*)(tail + 8192);           // [8192]
    int*   amax_bits = (int*)(tail + 8192 + 32768);     // [8192]
    // total: ~196.3 MiB
    _Float16* xh = (_Float16*)d_out;  // x fp16; dead before GEMM2 writes out

    init_amax_kernel<<<T_TOK / 256, 256, 0, stream>>>(amax_bits);
    quant_ug_kernel<0><<<I_DIM, 256, 0, stream>>>(Wg, Wq_ug);
    quant_ug_kernel<1><<<I_DIM, 256, 0, stream>>>(Wu, Wq_ug);
    quant_wd_i8_kernel<<<H_DIM, 256, 0, stream>>>(Wd, Qw_d, sw);
    cast_x_kernel<<<(T_TOK * H_DIM) / 1024, 256, 0, stream>>>(x, xh);

    gemm1_fused_kernel<<<dim3((T_TOK / 256) * (N1 / 256)), 512, 0, stream>>>(
        xh, Wq_ug, mulh, amax_bits);

    act_quant_kernel<<<T_TOK, 256, 0, stream>>>(mulh, amax_bits, qa, sa);

    gemm2_i8_kernel<<<dim3((T_TOK / 256) * (H_DIM / 256)), 512, 0, stream>>>(
        qa, Qw_d, sa, sw, out);
}

// Round 5
// 722.219 us; speedup vs baseline: 1.0642x; 1.0642x over previous
//
#include <hip/hip_runtime.h>

// ---------------------------------------------------------------------------
// QuantMLP r9: RECOMBINATION of best-measured components. r8's read-rebalance
// regressed gemm1 507us vs r7's 413us (draining the VMEM queue to 4 at
// BARRIER1, before B(t+2) was issued, kills memory-level parallelism; r7's
// p3-wait kept >=8 loads in flight at all times). r8's gemm2 256x256-pipeline
// port WORKED (rest-of-pipeline 344->261us). r9 = r7's gemm1 (verbatim) +
// r8's gemm2 (verbatim). No new variables; clean attribution baseline for
// the next gemm1 experiment.
// gemm1: 256x256, BK=64, A triple-buffered (96KiB) + B double (64KiB),
//        2-tile prefetch, vmcnt(8) once per tile at p3, reads 1 phase ahead.
// gemm2: same structure, BK=128 i8, NT=44, grid=256 blocks = 1/CU.
// Shapes: T=8192 tokens, H=2048, I=5632.
// ---------------------------------------------------------------------------

#define DEVI __device__ __forceinline__

typedef _Float16 half8 __attribute__((ext_vector_type(8)));
typedef _Float16 half4v __attribute__((ext_vector_type(4)));
typedef float floatx4 __attribute__((ext_vector_type(4)));
typedef int int4v __attribute__((ext_vector_type(4)));
typedef signed char char8v __attribute__((ext_vector_type(8)));

static constexpr int T_TOK = 8192;   // B*S
static constexpr int H_DIM = 2048;
static constexpr int I_DIM = 5632;
static constexpr int N1 = 2 * I_DIM; // 11264: interleaved [16 gate | 16 up]*

DEVI void load16_lds(const void* g, void* l) {
    __builtin_amdgcn_global_load_lds(
        (const __attribute__((address_space(1))) unsigned int*)g,
        (__attribute__((address_space(3))) unsigned int*)l,
        16 /*bytes*/, 0 /*offset*/, 0 /*aux*/);
}

DEVI float block_amax_256(float v, float* sbuf) {
    #pragma unroll
    for (int off = 32; off; off >>= 1)
        v = fmaxf(v, __shfl_xor(v, off, 64));
    if ((threadIdx.x & 63) == 0) sbuf[threadIdx.x >> 6] = v;
    __syncthreads();
    return fmaxf(fmaxf(sbuf[0], sbuf[1]), fmaxf(sbuf[2], sbuf[3]));
}

// ------------------------- init per-token amax ------------------------------
__global__ __launch_bounds__(256) void init_amax_kernel(int* __restrict__ a) {
    a[blockIdx.x * 256 + threadIdx.x] = 0;  // float 0.0 bit pattern
}

// ------------------ Wg/Wu 4-bit fake-quant, interleaved out -----------------
// source row i -> dest row (i>>4)*32 + HALF*16 + (i&15)  (HALF: 0=gate,1=up)
template <int HALF>
__global__ __launch_bounds__(256) void quant_ug_kernel(
    const float* __restrict__ in, _Float16* __restrict__ out) {
    __shared__ float sbuf[4];
    const int i = blockIdx.x;
    const int orow = ((i >> 4) * 32) + HALF * 16 + (i & 15);
    const float* r = in + (size_t)i * H_DIM;
    _Float16* o = out + (size_t)orow * H_DIM;
    float v[8];
    float amax = 0.f;
    #pragma unroll
    for (int j = 0; j < 8; ++j) {
        v[j] = r[threadIdx.x + j * 256];
        amax = fmaxf(amax, fabsf(v[j]));
    }
    amax = block_amax_256(amax, sbuf);
    const float scale = fmaxf(amax / 7.f, 1e-8f);
    #pragma unroll
    for (int j = 0; j < 8; ++j) {
        float q = rintf(v[j] / scale);
        q = fminf(fmaxf(q, -7.f), 7.f);
        o[threadIdx.x + j * 256] = (_Float16)(q * scale);
    }
}

// ------------------ Wd 4-bit quant -> int8 codes + scale --------------------
__global__ __launch_bounds__(256) void quant_wd_i8_kernel(
    const float* __restrict__ in, signed char* __restrict__ qw,
    float* __restrict__ sw) {
    __shared__ float sbuf[4];
    const size_t row = blockIdx.x;
    const float* r = in + row * (size_t)I_DIM;
    signed char* o = qw + row * (size_t)I_DIM;
    float v[22];
    float amax = 0.f;
    #pragma unroll
    for (int j = 0; j < 22; ++j) {
        v[j] = r[threadIdx.x + j * 256];
        amax = fmaxf(amax, fabsf(v[j]));
    }
    amax = block_amax_256(amax, sbuf);
    const float scale = fmaxf(amax / 7.f, 1e-8f);
    if (threadIdx.x == 0) sw[row] = scale;
    #pragma unroll
    for (int j = 0; j < 22; ++j) {
        float q = rintf(v[j] / scale);
        q = fminf(fmaxf(q, -7.f), 7.f);
        o[threadIdx.x + j * 256] = (signed char)q;
    }
}

// --------------------------- x cast fp32 -> fp16 ----------------------------
__global__ __launch_bounds__(256) void cast_x_kernel(
    const float* __restrict__ in, _Float16* __restrict__ out) {
    const size_t i = ((size_t)blockIdx.x * 256 + threadIdx.x) * 4;
    floatx4 f = *(const floatx4*)(in + i);
    half4v h;
    h.x = (_Float16)f.x; h.y = (_Float16)f.y;
    h.z = (_Float16)f.z; h.w = (_Float16)f.w;
    *(half4v*)(out + i) = h;
}

// ---------------- GEMM1: 256x256 tile, BK=64, 8 waves, 2-tile prefetch ------
// (verbatim r7, best-measured 413us / 913 TF)
// LDS 160 KiB: A [3 buf][2 half][128][64] f16 (96 KiB, buf = t%3),
//              B [2 buf][2 half][128][64] f16 (64 KiB, buf = t&1).
// XOR-swizzled (linear glds dest + inverse-swizzled global src + swz read).
// Per tile t (quadrant phases, fragment reads 1 phase ahead of their MFMA):
//   p0: read bf1(t);  STAGE A(t+2,h0)->Abuf[(t+2)%3] | M00 (ops read @p3 t-1)
//   p1: read af1(t);  STAGE A(t+2,h1)                | M01;  BARRIER1
//   p2:               STAGE B(t+2,h0)+B(t+2,h1)->Bbuf[t&1] | M10
//   p3: vmcnt(8) [waits A(t+1),B(t+1); keeps A(t+2),B(t+2)]; BARRIER2;
//       read af0/bf0(t+1) from next bufs             | M11 (no lgkm wait)
__global__ __launch_bounds__(512, 2) void gemm1_fused_kernel(
    const _Float16* __restrict__ A,   // xh [8192][2048]
    const _Float16* __restrict__ B,   // Wq_ug interleaved [11264][2048]
    _Float16* __restrict__ mulh,      // [8192][5632]
    int* __restrict__ amax_bits) {    // [8192], pre-zeroed
    __shared__ __align__(16) _Float16 As[3 * 2 * 128 * 64];  // 96 KiB
    __shared__ __align__(16) _Float16 Bs[2 * 2 * 128 * 64];  // 64 KiB

    constexpr int NT = H_DIM / 64;            // 32 K-tiles
    constexpr int NXB = N1 / 256;             // 44
    constexpr int NWG = (T_TOK / 256) * NXB;  // 1408 (divisible by 8)

    const int tid = threadIdx.x;
    const int lane = tid & 63;
    const int w = tid >> 6;        // 0..7
    const int wm = w >> 2;         // 0..1 (M half)
    const int wn = w & 3;          // 0..3 (N quarter)
    const int fr = lane & 15;
    const int q = lane >> 4;

    // XCD-aware swizzle (bijective: NWG % 8 == 0)
    int wg = blockIdx.x;
    wg = (wg & 7) * (NWG / 8) + (wg >> 3);
    const int by = wg / NXB;
    const int bx = wg - by * NXB;
    const int row0 = by * 256;
    const int col0 = bx * 256;

    // ---- staging addressing: linear LDS dest, inverse-swizzled global src --
    const int sr = tid >> 3;                         // 0..63
    const int sc = ((tid & 7) ^ (sr & 7)) << 3;      // swizzled col (f16)
    const _Float16* gA = A + (size_t)(row0 + sr) * H_DIM + sc;
    const _Float16* gB = B + (size_t)(col0 + sr) * H_DIM + sc;
    _Float16* lA = As + tid * 8;
    _Float16* lB = Bs + tid * 8;

    #define STAGE_A(t, h, buf) do {                                          \
        const _Float16* s_ = gA + (size_t)((h) * 128) * H_DIM + (t) * 64;    \
        _Float16* d_ = lA + ((buf) * 2 + (h)) * 8192;                        \
        load16_lds(s_, d_);                                                  \
        load16_lds(s_ + (size_t)64 * H_DIM, d_ + 4096);                      \
    } while (0)
    #define STAGE_B(t, h, buf) do {                                          \
        const _Float16* s_ = gB + (size_t)((h) * 128) * H_DIM + (t) * 64;    \
        _Float16* d_ = lB + ((buf) * 2 + (h)) * 8192;                        \
        load16_lds(s_, d_);                                                  \
        load16_lds(s_ + (size_t)64 * H_DIM, d_ + 4096);                      \
    } while (0)

    // ---- ds_read addressing (swizzled): elem = row*64 + (slot^(row&7))*8 --
    int coff[2];
    coff[0] = ((0 + q) ^ (fr & 7)) * 8;   // kk=0 slots 0..3
    coff[1] = ((4 + q) ^ (fr & 7)) * 8;   // kk=1 slots 4..7
    const int aro = wm * 8192 + fr * 64;                        // A half = wm
    const int bro = (wn >> 1) * 8192 + ((wn & 1) * 64 + fr) * 64;

    floatx4 acc[8][4] = {};
    half8 af0[4][2], af1[4][2], bf0[2][2], bf1[2][2];

    // ------------------------------- prologue -------------------------------
    // issue order: A(0) B(0) A(1) B(1) -> vmcnt(8) waits A(0),B(0)
    STAGE_A(0, 0, 0); STAGE_A(0, 1, 0);
    STAGE_B(0, 0, 0); STAGE_B(0, 1, 0);
    STAGE_A(1, 0, 1); STAGE_A(1, 1, 1);
    STAGE_B(1, 0, 1); STAGE_B(1, 1, 1);
    asm volatile("s_waitcnt vmcnt(8)" ::: "memory");  // A(0),B(0) resident
    __builtin_amdgcn_s_barrier();
    __builtin_amdgcn_sched_barrier(0);
    // pre-issue tile-0 af0/bf0 (bufs 0)
    #pragma unroll
    for (int mi = 0; mi < 4; ++mi)
        #pragma unroll
        for (int kk = 0; kk < 2; ++kk)
            af0[mi][kk] = *(const half8*)(As + aro + mi * 1024 + coff[kk]);
    #pragma unroll
    for (int ni = 0; ni < 2; ++ni)
        #pragma unroll
        for (int kk = 0; kk < 2; ++kk)
            bf0[ni][kk] = *(const half8*)(Bs + bro + ni * 1024 + coff[kk]);

    int ra = 0;  // A read buf = t%3
    for (int t = 0; t < NT; ++t) {
        const int bufb = t & 1;
        const int na = (ra == 2) ? 0 : ra + 1;   // (t+1)%3
        const int wa = (na == 2) ? 0 : na + 1;   // (t+2)%3
        const int ab = ra * 16384 + aro;
        const int bb = bufb * 16384 + bro;
        const int nab = na * 16384 + aro;
        const int nbb = (bufb ^ 1) * 16384 + bro;

        // -------- p0: read bf1(t); STAGE A(t+2,h0); M00 = af0*bf0 ----------
        #pragma unroll
        for (int ni = 0; ni < 2; ++ni)
            #pragma unroll
            for (int kk = 0; kk < 2; ++kk)
                bf1[ni][kk] =
                    *(const half8*)(Bs + bb + (2 + ni) * 1024 + coff[kk]);
        if (t + 2 < NT) STAGE_A(t + 2, 0, wa);
        __builtin_amdgcn_s_setprio(1);
        #pragma unroll
        for (int mi = 0; mi < 4; ++mi)
            #pragma unroll
            for (int ni = 0; ni < 2; ++ni)
                #pragma unroll
                for (int kk = 0; kk < 2; ++kk)
                    acc[mi][ni] = __builtin_amdgcn_mfma_f32_16x16x32_f16(
                        af0[mi][kk], bf0[ni][kk], acc[mi][ni], 0, 0, 0);
        __builtin_amdgcn_s_setprio(0);

        // -------- p1: read af1(t); STAGE A(t+2,h1); M01 = af0*bf1; BARRIER1
        #pragma unroll
        for (int mi = 0; mi < 4; ++mi)
            #pragma unroll
            for (int kk = 0; kk < 2; ++kk)
                af1[mi][kk] =
                    *(const half8*)(As + ab + (4 + mi) * 1024 + coff[kk]);
        if (t + 2 < NT) STAGE_A(t + 2, 1, wa);
        __builtin_amdgcn_s_setprio(1);
        #pragma unroll
        for (int mi = 0; mi < 4; ++mi)
            #pragma unroll
            for (int ni = 0; ni < 2; ++ni)
                #pragma unroll
                for (int kk = 0; kk < 2; ++kk)
                    acc[mi][2 + ni] = __builtin_amdgcn_mfma_f32_16x16x32_f16(
                        af0[mi][kk], bf1[ni][kk], acc[mi][2 + ni], 0, 0, 0);
        __builtin_amdgcn_s_setprio(0);
        __builtin_amdgcn_s_barrier();          // BARRIER1
        __builtin_amdgcn_sched_barrier(0);

        // -------- p2: STAGE B(t+2,h0)+B(t+2,h1); M10 = af1*bf0 -------------
        if (t + 2 < NT) { STAGE_B(t + 2, 0, bufb); STAGE_B(t + 2, 1, bufb); }
        __builtin_amdgcn_s_setprio(1);
        #pragma unroll
        for (int mi = 0; mi < 4; ++mi)
            #pragma unroll
            for (int ni = 0; ni < 2; ++ni)
                #pragma unroll
                for (int kk = 0; kk < 2; ++kk)
                    acc[4 + mi][ni] = __builtin_amdgcn_mfma_f32_16x16x32_f16(
                        af1[mi][kk], bf0[ni][kk], acc[4 + mi][ni], 0, 0, 0);
        __builtin_amdgcn_s_setprio(0);

        // -------- p3: vmcnt(8); BARRIER2; read af0/bf0(t+1); M11 -----------
        if (t < NT - 2)
            asm volatile("s_waitcnt vmcnt(8)" ::: "memory");  // t+1 resident
        else
            asm volatile("s_waitcnt vmcnt(0)" ::: "memory");  // tail drain
        __builtin_amdgcn_s_barrier();          // BARRIER2
        __builtin_amdgcn_sched_barrier(0);
        if (t + 1 < NT) {
            #pragma unroll
            for (int mi = 0; mi < 4; ++mi)
                #pragma unroll
                for (int kk = 0; kk < 2; ++kk)
                    af0[mi][kk] =
                        *(const half8*)(As + nab + mi * 1024 + coff[kk]);
            #pragma unroll
            for (int ni = 0; ni < 2; ++ni)
                #pragma unroll
                for (int kk = 0; kk < 2; ++kk)
                    bf0[ni][kk] =
                        *(const half8*)(Bs + nbb + ni * 1024 + coff[kk]);
        }
        __builtin_amdgcn_s_setprio(1);
        #pragma unroll
        for (int mi = 0; mi < 4; ++mi)
            #pragma unroll
            for (int ni = 0; ni < 2; ++ni)
                #pragma unroll
                for (int kk = 0; kk < 2; ++kk)
                    acc[4 + mi][2 + ni] =
                        __builtin_amdgcn_mfma_f32_16x16x32_f16(
                            af1[mi][kk], bf1[ni][kk], acc[4 + mi][2 + ni],
                            0, 0, 0);
        __builtin_amdgcn_s_setprio(0);
        ra = na;
    }
    #undef STAGE_A
    #undef STAGE_B

    // ---- fused epilogue: silu(gate)*up in-register + per-token amax --------
    const int q4 = q * 4;
    const int lc = fr;
    _Float16* mbase = mulh + bx * 128 + wn * 32 + lc;
    #pragma unroll
    for (int mi = 0; mi < 8; ++mi) {
        #pragma unroll
        for (int i = 0; i < 4; ++i) {
            const int r = row0 + wm * 128 + mi * 16 + q4 + i;
            float rmax = 0.f;
            _Float16* mrow = mbase + (size_t)r * I_DIM;
            #pragma unroll
            for (int p = 0; p < 2; ++p) {
                const float g = acc[mi][2 * p][i];
                const float u = acc[mi][2 * p + 1][i];
                const float m = g / (1.f + expf(-g)) * u;  // silu(g)*u
                mrow[p * 16] = (_Float16)m;
                rmax = fmaxf(rmax, fabsf(m));
            }
            #pragma unroll
            for (int off = 1; off < 16; off <<= 1)
                rmax = fmaxf(rmax, __shfl_xor(rmax, off, 64));
            if (lc == 0)
                atomicMax(&amax_bits[r], __float_as_int(rmax));
        }
    }
}

// ---------------- per-token 8-bit quant: fp16 mul -> int8 codes -------------
__global__ __launch_bounds__(256) void act_quant_kernel(
    const _Float16* __restrict__ mulh, const int* __restrict__ amax_bits,
    signed char* __restrict__ qa, float* __restrict__ sa) {
    const size_t t = blockIdx.x;
    const float amax = __int_as_float(amax_bits[t]);
    const float s = fmaxf(amax / 127.f, 1e-8f);
    if (threadIdx.x == 0) sa[t] = s;
    const float rs = 1.f / s;
    const _Float16* mrow = mulh + t * I_DIM;
    signed char* qrow = qa + t * I_DIM;
    for (int c = threadIdx.x; c < I_DIM / 8; c += 256) {
        half8 v = *(const half8*)(mrow + c * 8);
        char8v q;
        #pragma unroll
        for (int j = 0; j < 8; ++j) {
            float f = rintf((float)v[j] * rs);
            f = fminf(fmaxf(f, -127.f), 127.f);
            q[j] = (signed char)f;
        }
        *(char8v*)(qrow + c * 8) = q;
    }
}

// ------------- GEMM2: int8 down-proj, 256x256 pipelined (exact) -------------
// (verbatim r8, best-measured: rest-of-pipeline 344 -> 261us)
// Same structure/schedule as gemm1-r8 (BK=128 i8 -> byte-identical LDS
// layout: [128 rows][128B] halves, same swizzle/staging/fragment geometry).
// NT=44 K-tiles; grid = 256 blocks = exactly 1/CU. int32 accum = associative
// -> bitwise identical results to any schedule.
__global__ __launch_bounds__(512, 2) void gemm2_i8_kernel(
    const signed char* __restrict__ A,  // qa [8192][5632]
    const signed char* __restrict__ B,  // Qw_d [2048][5632]
    const float* __restrict__ sa, const float* __restrict__ sw,
    float* __restrict__ C) {            // [8192][2048]
    __shared__ __align__(16) signed char As[3 * 2 * 128 * 128];  // 96 KiB
    __shared__ __align__(16) signed char Bs[2 * 2 * 128 * 128];  // 64 KiB

    constexpr int NT = I_DIM / 128;           // 44 K-tiles
    constexpr int NXB = H_DIM / 256;          // 8
    constexpr int NWG = (T_TOK / 256) * NXB;  // 256 (exactly 1/CU)

    const int tid = threadIdx.x;
    const int lane = tid & 63;
    const int w = tid >> 6;
    const int wm = w >> 2;         // 0..1
    const int wn = w & 3;          // 0..3
    const int fr = lane & 15;
    const int q = lane >> 4;

    int wg = blockIdx.x;
    wg = (wg & 7) * (NWG / 8) + (wg >> 3);   // XCD swizzle, bijective
    const int by = wg / NXB;
    const int bx = wg - by * NXB;
    const int row0 = by * 256;
    const int col0 = bx * 256;

    // staging: linear LDS dest, inverse-swizzled global src (16B units)
    const int sr = tid >> 3;                          // 0..63
    const int scb = ((tid & 7) ^ (sr & 7)) << 4;      // swizzled byte col
    const signed char* gA = A + (size_t)(row0 + sr) * I_DIM + scb;
    const signed char* gB = B + (size_t)(col0 + sr) * I_DIM + scb;
    signed char* lA = As + tid * 16;
    signed char* lB = Bs + tid * 16;

    #define STAGE_A2(t, h, buf) do {                                         \
        const signed char* s_ = gA + (size_t)((h) * 128) * I_DIM + (t) * 128;\
        signed char* d_ = lA + ((buf) * 2 + (h)) * 16384;                    \
        load16_lds(s_, d_);                                                  \
        load16_lds(s_ + (size_t)64 * I_DIM, d_ + 8192);                      \
    } while (0)
    #define STAGE_B2(t, h, buf) do {                                         \
        const signed char* s_ = gB + (size_t)((h) * 128) * I_DIM + (t) * 128;\
        signed char* d_ = lB + ((buf) * 2 + (h)) * 16384;                    \
        load16_lds(s_, d_);                                                  \
        load16_lds(s_ + (size_t)64 * I_DIM, d_ + 8192);                      \
    } while (0)

    // ds_read (swizzled): byte = row*128 + ((kk*4+q)^(row&7))*16
    int coff[2];
    coff[0] = ((0 + q) ^ (fr & 7)) * 16;
    coff[1] = ((4 + q) ^ (fr & 7)) * 16;
    const int aro = wm * 16384 + fr * 128;
    const int bro = (wn >> 1) * 16384 + ((wn & 1) * 64 + fr) * 128;

    int4v acc[8][4] = {};
    int4v af0[4][2], af1[4][2], bf0[2][2], bf1[2][2];

    // prologue
    STAGE_A2(0, 0, 0); STAGE_A2(0, 1, 0);
    STAGE_B2(0, 0, 0); STAGE_B2(0, 1, 0);
    STAGE_A2(1, 0, 1); STAGE_A2(1, 1, 1);
    STAGE_B2(1, 0, 1); STAGE_B2(1, 1, 1);
    asm volatile("s_waitcnt vmcnt(8)" ::: "memory");
    __builtin_amdgcn_s_barrier();
    __builtin_amdgcn_sched_barrier(0);
    #pragma unroll
    for (int mi = 0; mi < 4; ++mi)
        #pragma unroll
        for (int kk = 0; kk < 2; ++kk)
            af0[mi][kk] = *(const int4v*)(As + aro + mi * 2048 + coff[kk]);
    #pragma unroll
    for (int ni = 0; ni < 2; ++ni)
        #pragma unroll
        for (int kk = 0; kk < 2; ++kk)
            bf0[ni][kk] = *(const int4v*)(Bs + bro + ni * 2048 + coff[kk]);

    int ra = 0;
    for (int t = 0; t < NT; ++t) {
        const int bufb = t & 1;
        const int na = (ra == 2) ? 0 : ra + 1;
        const int wa = (na == 2) ? 0 : na + 1;
        const int ab = ra * 32768 + aro;
        const int bb = bufb * 32768 + bro;
        const int nab = na * 32768 + aro;
        const int nbb = (bufb ^ 1) * 32768 + bro;

        // p0
        #pragma unroll
        for (int ni = 0; ni < 2; ++ni)
            #pragma unroll
            for (int kk = 0; kk < 2; ++kk)
                bf1[ni][kk] =
                    *(const int4v*)(Bs + bb + (2 + ni) * 2048 + coff[kk]);
        #pragma unroll
        for (int mi = 0; mi < 2; ++mi)
            #pragma unroll
            for (int kk = 0; kk < 2; ++kk)
                af1[mi][kk] =
                    *(const int4v*)(As + ab + (4 + mi) * 2048 + coff[kk]);
        if (t + 2 < NT) STAGE_A2(t + 2, 0, wa);
        __builtin_amdgcn_s_setprio(1);
        #pragma unroll
        for (int mi = 0; mi < 4; ++mi)
            #pragma unroll
            for (int ni = 0; ni < 2; ++ni)
                #pragma unroll
                for (int kk = 0; kk < 2; ++kk)
                    acc[mi][ni] = __builtin_amdgcn_mfma_i32_16x16x64_i8(
                        af0[mi][kk], bf0[ni][kk], acc[mi][ni], 0, 0, 0);
        __builtin_amdgcn_s_setprio(0);

        // p1
        #pragma unroll
        for (int mi = 2; mi < 4; ++mi)
            #pragma unroll
            for (int kk = 0; kk < 2; ++kk)
                af1[mi][kk] =
                    *(const int4v*)(As + ab + (4 + mi) * 2048 + coff[kk]);
        if (t + 2 < NT) STAGE_A2(t + 2, 1, wa);
        __builtin_amdgcn_s_setprio(1);
        #pragma unroll
        for (int mi = 0; mi < 4; ++mi)
            #pragma unroll
            for (int ni = 0; ni < 2; ++ni)
                #pragma unroll
                for (int kk = 0; kk < 2; ++kk)
                    acc[mi][2 + ni] = __builtin_amdgcn_mfma_i32_16x16x64_i8(
                        af0[mi][kk], bf1[ni][kk], acc[mi][2 + ni], 0, 0, 0);
        __builtin_amdgcn_s_setprio(0);
        if (t + 2 < NT)
            asm volatile("s_waitcnt vmcnt(4)" ::: "memory");
        else
            asm volatile("s_waitcnt vmcnt(0)" ::: "memory");
        __builtin_amdgcn_s_barrier();          // BARRIER1
        __builtin_amdgcn_sched_barrier(0);

        // p2
        if (t + 1 < NT) {
            #pragma unroll
            for (int mi = 0; mi < 2; ++mi)
                #pragma unroll
                for (int kk = 0; kk < 2; ++kk)
                    af0[mi][kk] =
                        *(const int4v*)(As + nab + mi * 2048 + coff[kk]);
        }
        if (t + 2 < NT) { STAGE_B2(t + 2, 0, bufb); STAGE_B2(t + 2, 1, bufb); }
        __builtin_amdgcn_s_setprio(1);
        #pragma unroll
        for (int mi = 0; mi < 4; ++mi)
            #pragma unroll
            for (int ni = 0; ni < 2; ++ni)
                #pragma unroll
                for (int kk = 0; kk < 2; ++kk)
                    acc[4 + mi][ni] = __builtin_amdgcn_mfma_i32_16x16x64_i8(
                        af1[mi][kk], bf0[ni][kk], acc[4 + mi][ni], 0, 0, 0);
        __builtin_amdgcn_s_setprio(0);

        // p3
        if (t + 1 < NT) {
            #pragma unroll
            for (int mi = 2; mi < 4; ++mi)
                #pragma unroll
                for (int kk = 0; kk < 2; ++kk)
                    af0[mi][kk] =
                        *(const int4v*)(As + nab + mi * 2048 + coff[kk]);
            #pragma unroll
            for (int ni = 0; ni < 2; ++ni)
                #pragma unroll
                for (int kk = 0; kk < 2; ++kk)
                    bf0[ni][kk] =
                        *(const int4v*)(Bs + nbb + ni * 2048 + coff[kk]);
        }
        __builtin_amdgcn_s_setprio(1);
        #pragma unroll
        for (int mi = 0; mi < 4; ++mi)
            #pragma unroll
            for (int ni = 0; ni < 2; ++ni)
                #pragma unroll
                for (int kk = 0; kk < 2; ++kk)
                    acc[4 + mi][2 + ni] =
                        __builtin_amdgcn_mfma_i32_16x16x64_i8(
                            af1[mi][kk], bf1[ni][kk], acc[4 + mi][2 + ni],
                            0, 0, 0);
        __builtin_amdgcn_s_setprio(0);
        __builtin_amdgcn_s_barrier();          // BARRIER2
        __builtin_amdgcn_sched_barrier(0);
        ra = na;
    }
    #undef STAGE_A2
    #undef STAGE_B2

    // epilogue: scale and store
    const int q4 = q * 4;
    float sw4[4];
    #pragma unroll
    for (int ni = 0; ni < 4; ++ni)
        sw4[ni] = sw[col0 + wn * 64 + ni * 16 + fr];
    #pragma unroll
    for (int mi = 0; mi < 8; ++mi) {
        #pragma unroll
        for (int i = 0; i < 4; ++i) {
            const int r = row0 + wm * 128 + mi * 16 + q4 + i;
            const float s_r = sa[r];
            float* crow = C + (size_t)r * H_DIM + col0 + wn * 64 + fr;
            #pragma unroll
            for (int ni = 0; ni < 4; ++ni)
                crow[ni * 16] = (float)acc[mi][ni][i] * s_r * sw4[ni];
        }
    }
}

// ---------------------------------------------------------------------------
extern "C" void kernel_launch(void* const* d_in, const int* in_sizes, int n_in,
                              void* d_out, int out_size, void* d_ws, size_t ws_size,
                              hipStream_t stream) {
    const float* x  = (const float*)d_in[0];   // [8192, 2048]
    const float* Wg = (const float*)d_in[1];   // [5632, 2048]
    const float* Wu = (const float*)d_in[2];   // [5632, 2048]
    const float* Wd = (const float*)d_in[3];   // [2048, 5632]
    float* out = (float*)d_out;                // [8192, 2048] = 64 MiB

    char* ws = (char*)d_ws;
    const size_t SZ_WUG  = (size_t)N1 * H_DIM * 2;     // 46,137,344
    const size_t SZ_MULH = (size_t)T_TOK * I_DIM * 2;  // 92,274,688
    const size_t SZ_QA   = (size_t)T_TOK * I_DIM;      // 46,137,344
    const size_t SZ_QWD  = (size_t)H_DIM * I_DIM;      // 11,534,336
    _Float16*    Wq_ug = (_Float16*)ws;
    _Float16*    mulh  = (_Float16*)(ws + SZ_WUG);
    signed char* qa    = (signed char*)(ws + SZ_WUG + SZ_MULH);
    signed char* Qw_d  = (signed char*)(ws + SZ_WUG + SZ_MULH + SZ_QA);
    char* tail = ws + SZ_WUG + SZ_MULH + SZ_QA + SZ_QWD;
    float* sw        = (float*)tail;                    // [2048]
    float* sa        = (float*)(tail + 8192);           // [8192]
    int*   amax_bits = (int*)(tail + 8192 + 32768);     // [8192]
    // total: ~196.3 MiB
    _Float16* xh = (_Float16*)d_out;  // x fp16; dead before GEMM2 writes out

    init_amax_kernel<<<T_TOK / 256, 256, 0, stream>>>(amax_bits);
    quant_ug_kernel<0><<<I_DIM, 256, 0, stream>>>(Wg, Wq_ug);
    quant_ug_kernel<1><<<I_DIM, 256, 0, stream>>>(Wu, Wq_ug);
    quant_wd_i8_kernel<<<H_DIM, 256, 0, stream>>>(Wd, Qw_d, sw);
    cast_x_kernel<<<(T_TOK * H_DIM) / 1024, 256, 0, stream>>>(x, xh);

    gemm1_fused_kernel<<<dim3((T_TOK / 256) * (N1 / 256)), 512, 0, stream>>>(
        xh, Wq_ug, mulh, amax_bits);

    act_quant_kernel<<<T_TOK, 256, 0, stream>>>(mulh, amax_bits, qa, sa);

    gemm2_i8_kernel<<<dim3((T_TOK / 256) * (H_DIM / 256)), 512, 0, stream>>>(
        qa, Qw_d, sa, sw, out);
}